// Round 2
// baseline (976.998 us; speedup 1.0000x reference)
//
#include <hip/hip_runtime.h>
#include <hip/hip_bf16.h>

#define C_    768
#define NH_   8
#define DH_   96
#define S_    729
#define B_    8
#define MTOK  5832
#define C3    2304
#define GUN   12288
#define DK    6144
#define SPAD  736
#define NPB   559872   // C_*S_

typedef __attribute__((ext_vector_type(8))) short short8;
typedef __attribute__((ext_vector_type(4))) float f32x4;
typedef __attribute__((ext_vector_type(4))) unsigned int uint4v;
typedef __hip_bfloat16 bf16;

__device__ __forceinline__ void gld_lds16(const bf16* g, bf16* l) {
  __builtin_amdgcn_global_load_lds((const __attribute__((address_space(1))) void*)g,
                                   (__attribute__((address_space(3))) void*)l, 16, 0, 0);
}

// ---------------- plain bf16 GEMM, C = A @ Bt^T  (Bt is [N][K]) ----------------
__global__ void __launch_bounds__(256)
gemm_bt(const bf16* __restrict__ A, long a_rs, long a_oo, long a_oi,
        const bf16* __restrict__ Bt, long b_rs, long b_oo, long b_oi,
        float* __restrict__ Cf, bf16* __restrict__ Cb,
        long c_rs, long c_oo, long c_oi,
        int M, int N, int K, int nlim, int zdiv)
{
  __shared__ bf16 ldsA[128*32];
  __shared__ bf16 ldsB[128*32];
  const int tid = threadIdx.x;
  const int wid = tid >> 6;
  const int lid = tid & 63;
  const int z = blockIdx.z;
  const int zo = z / zdiv, zi = z - zo*zdiv;
  A  += (long)zo*a_oo + (long)zi*a_oi;
  Bt += (long)zo*b_oo + (long)zi*b_oi;
  const long cbase = (long)zo*c_oo + (long)zi*c_oi;
  const int brow = blockIdx.y * 128;
  const int bcol = blockIdx.x * 128;

  const int ch0 = tid, ch1 = tid + 256;
  const int ar0 = ch0 >> 2, ar1 = ch1 >> 2;
  const int ak0 = (ch0 & 3) * 8, ak1 = (ch1 & 3) * 8;
  int ra0 = brow + ar0; if (ra0 > M-1) ra0 = M-1;
  int ra1 = brow + ar1; if (ra1 > M-1) ra1 = M-1;
  int rb0 = bcol + ar0; if (rb0 > N-1) rb0 = N-1;
  int rb1 = bcol + ar1; if (rb1 > N-1) rb1 = N-1;
  const bf16* pa0 = A + (long)ra0*a_rs + ak0;
  const bf16* pa1 = A + (long)ra1*a_rs + ak1;
  const bf16* pb0 = Bt + (long)rb0*b_rs + ak0;
  const bf16* pb1 = Bt + (long)rb1*b_rs + ak1;
  bf16* la0 = (bf16*)((char*)ldsA + wid*1024);
  bf16* la1 = (bf16*)((char*)ldsA + 4096 + wid*1024);
  bf16* lb0 = (bf16*)((char*)ldsB + wid*1024);
  bf16* lb1 = (bf16*)((char*)ldsB + 4096 + wid*1024);

  f32x4 acc[4][4] = {};
  const int wm = wid >> 1, wn = wid & 1;
  const int fr = lid & 15, g8 = (lid >> 4) * 8;

  for (int kt = 0; kt < K; kt += 32) {
    __syncthreads();
    gld_lds16(pa0 + kt, la0);
    gld_lds16(pa1 + kt, la1);
    gld_lds16(pb0 + kt, lb0);
    gld_lds16(pb1 + kt, lb1);
    __syncthreads();
    short8 af[4], bf[4];
    #pragma unroll
    for (int m = 0; m < 4; ++m)
      af[m] = *(const short8*)&ldsA[(wm*64 + m*16 + fr)*32 + g8];
    #pragma unroll
    for (int n = 0; n < 4; ++n)
      bf[n] = *(const short8*)&ldsB[(wn*64 + n*16 + fr)*32 + g8];
    #pragma unroll
    for (int m = 0; m < 4; ++m)
      #pragma unroll
      for (int n = 0; n < 4; ++n)
        acc[m][n] = __builtin_amdgcn_mfma_f32_16x16x32_bf16(af[m], bf[n], acc[m][n], 0, 0, 0);
  }

  const int rg = (lid >> 4) * 4;
  #pragma unroll
  for (int m = 0; m < 4; ++m) {
    #pragma unroll
    for (int n = 0; n < 4; ++n) {
      const int col = bcol + wn*64 + n*16 + fr;
      if (col < nlim) {
        #pragma unroll
        for (int j = 0; j < 4; ++j) {
          const int row = brow + wm*64 + m*16 + rg + j;
          if (row < M) {
            long off = cbase + (long)row*c_rs + col;
            if (Cb) Cb[off] = __float2bfloat16(acc[m][n][j]);
            else    Cf[off] = acc[m][n][j];
          }
        }
      }
    }
  }
}

// ---------------- bf16x3 split GEMM: A=(Ah+Al), B=(Bh+Bl), 3 products ----------------
// out modes: Cl!=0 -> hi/lo bf16 pair; else Ch!=0 -> bf16; else fp32 to Cf.
__global__ void __launch_bounds__(256)
gemm3_bt(const bf16* __restrict__ Ah, const bf16* __restrict__ Al,
         long a_rs, long a_oo, long a_oi,
         const bf16* __restrict__ Bth, const bf16* __restrict__ Btl,
         long b_rs, long b_oo, long b_oi,
         float* __restrict__ Cf, bf16* __restrict__ Ch, bf16* __restrict__ Cl,
         long c_rs, long c_oo, long c_oi,
         int M, int N, int K, int nlim, int zdiv)
{
  __shared__ bf16 lAh[4096];
  __shared__ bf16 lAl[4096];
  __shared__ bf16 lBh[4096];
  __shared__ bf16 lBl[4096];
  const int tid = threadIdx.x;
  const int wid = tid >> 6;
  const int lid = tid & 63;
  const int z = blockIdx.z;
  const int zo = z / zdiv, zi = z - zo*zdiv;
  const long aoff = (long)zo*a_oo + (long)zi*a_oi;
  const long boff = (long)zo*b_oo + (long)zi*b_oi;
  const long cbase = (long)zo*c_oo + (long)zi*c_oi;
  const int brow = blockIdx.y * 128;
  const int bcol = blockIdx.x * 128;

  const int ch0 = tid, ch1 = tid + 256;
  int ra0 = brow + (ch0 >> 2); if (ra0 > M-1) ra0 = M-1;
  int ra1 = brow + (ch1 >> 2); if (ra1 > M-1) ra1 = M-1;
  int rb0 = bcol + (ch0 >> 2); if (rb0 > N-1) rb0 = N-1;
  int rb1 = bcol + (ch1 >> 2); if (rb1 > N-1) rb1 = N-1;
  const long ia0 = aoff + (long)ra0*a_rs + (ch0 & 3)*8;
  const long ia1 = aoff + (long)ra1*a_rs + (ch1 & 3)*8;
  const long ib0 = boff + (long)rb0*b_rs + (ch0 & 3)*8;
  const long ib1 = boff + (long)rb1*b_rs + (ch1 & 3)*8;
  bf16* dAh0 = (bf16*)((char*)lAh + wid*1024);
  bf16* dAh1 = (bf16*)((char*)lAh + 4096 + wid*1024);
  bf16* dAl0 = (bf16*)((char*)lAl + wid*1024);
  bf16* dAl1 = (bf16*)((char*)lAl + 4096 + wid*1024);
  bf16* dBh0 = (bf16*)((char*)lBh + wid*1024);
  bf16* dBh1 = (bf16*)((char*)lBh + 4096 + wid*1024);
  bf16* dBl0 = (bf16*)((char*)lBl + wid*1024);
  bf16* dBl1 = (bf16*)((char*)lBl + 4096 + wid*1024);

  f32x4 acc[4][4] = {};
  const int wm = wid >> 1, wn = wid & 1;
  const int fr = lid & 15, g8 = (lid >> 4) * 8;

  for (int kt = 0; kt < K; kt += 32) {
    __syncthreads();
    gld_lds16(Ah + ia0 + kt, dAh0);
    gld_lds16(Ah + ia1 + kt, dAh1);
    gld_lds16(Al + ia0 + kt, dAl0);
    gld_lds16(Al + ia1 + kt, dAl1);
    gld_lds16(Bth + ib0 + kt, dBh0);
    gld_lds16(Bth + ib1 + kt, dBh1);
    gld_lds16(Btl + ib0 + kt, dBl0);
    gld_lds16(Btl + ib1 + kt, dBl1);
    __syncthreads();
    short8 fah[4], fal[4], fbh[4], fbl[4];
    #pragma unroll
    for (int m = 0; m < 4; ++m) {
      int ro = (wm*64 + m*16 + fr)*32 + g8;
      fah[m] = *(const short8*)&lAh[ro];
      fal[m] = *(const short8*)&lAl[ro];
    }
    #pragma unroll
    for (int n = 0; n < 4; ++n) {
      int ro = (wn*64 + n*16 + fr)*32 + g8;
      fbh[n] = *(const short8*)&lBh[ro];
      fbl[n] = *(const short8*)&lBl[ro];
    }
    #pragma unroll
    for (int m = 0; m < 4; ++m)
      #pragma unroll
      for (int n = 0; n < 4; ++n) {
        acc[m][n] = __builtin_amdgcn_mfma_f32_16x16x32_bf16(fal[m], fbh[n], acc[m][n], 0, 0, 0);
        acc[m][n] = __builtin_amdgcn_mfma_f32_16x16x32_bf16(fah[m], fbl[n], acc[m][n], 0, 0, 0);
        acc[m][n] = __builtin_amdgcn_mfma_f32_16x16x32_bf16(fah[m], fbh[n], acc[m][n], 0, 0, 0);
      }
  }

  const int rg = (lid >> 4) * 4;
  #pragma unroll
  for (int m = 0; m < 4; ++m) {
    #pragma unroll
    for (int n = 0; n < 4; ++n) {
      const int col = bcol + wn*64 + n*16 + fr;
      if (col < nlim) {
        #pragma unroll
        for (int j = 0; j < 4; ++j) {
          const int row = brow + wm*64 + m*16 + rg + j;
          if (row < M) {
            long off = cbase + (long)row*c_rs + col;
            float v = acc[m][n][j];
            if (Cl) {
              bf16 h = __float2bfloat16(v);
              Ch[off] = h;
              Cl[off] = __float2bfloat16(v - __bfloat162float(h));
            } else if (Ch) {
              Ch[off] = __float2bfloat16(v);
            } else {
              Cf[off] = v;
            }
          }
        }
      }
    }
  }
}

// ---------------- weight transpose fp32 -> bf16, out[c][r] = in[r][c] ----------------
__global__ void wtrans(const float* __restrict__ in, bf16* __restrict__ out,
                       int R, int Cc, long in_rs, long out_rs, long in_bs, long out_bs)
{
  __shared__ float tile[32][33];
  in  += (long)blockIdx.z * in_bs;
  out += (long)blockIdx.z * out_bs;
  int r0 = blockIdx.y*32, c0 = blockIdx.x*32;
  int tx = threadIdx.x, ty = threadIdx.y;
  #pragma unroll
  for (int i = 0; i < 32; i += 8) {
    int r = r0 + ty + i, c = c0 + tx;
    if (r < R && c < Cc) tile[ty+i][tx] = in[(long)r*in_rs + c];
  }
  __syncthreads();
  #pragma unroll
  for (int i = 0; i < 32; i += 8) {
    int ro = c0 + ty + i, co = r0 + tx;
    if (ro < Cc && co < R) out[(long)ro*out_rs + co] = __float2bfloat16(tile[tx][ty+i]);
  }
}

// ---------------- weight transpose fp32 -> bf16 hi/lo pair ----------------
__global__ void wtrans3(const float* __restrict__ in, bf16* __restrict__ oh, bf16* __restrict__ ol,
                        int R, int Cc, long in_rs, long out_rs)
{
  __shared__ float tile[32][33];
  int r0 = blockIdx.y*32, c0 = blockIdx.x*32;
  int tx = threadIdx.x, ty = threadIdx.y;
  #pragma unroll
  for (int i = 0; i < 32; i += 8) {
    int r = r0 + ty + i, c = c0 + tx;
    if (r < R && c < Cc) tile[ty+i][tx] = in[(long)r*in_rs + c];
  }
  __syncthreads();
  #pragma unroll
  for (int i = 0; i < 32; i += 8) {
    int ro = c0 + ty + i, co = r0 + tx;
    if (ro < Cc && co < R) {
      float v = tile[tx][ty+i];
      bf16 h = __float2bfloat16(v);
      long o = (long)ro*out_rs + co;
      oh[o] = h;
      ol[o] = __float2bfloat16(v - __bfloat162float(h));
    }
  }
}

// ---------------- LayerNorm ----------------
__global__ void ln_partial(const float* __restrict__ x, float* __restrict__ part) {
  int b = blockIdx.y, blk = blockIdx.x;
  const float* xb = x + (long)b*NPB;
  int start = blk * 4374;
  float s = 0.f, ss = 0.f;
  for (int i = start + threadIdx.x; i < start + 4374; i += 256) {
    float v = xb[i]; s += v; ss += v*v;
  }
  #pragma unroll
  for (int o = 32; o; o >>= 1) { s += __shfl_down(s, o); ss += __shfl_down(ss, o); }
  __shared__ float red[2][4];
  int wid = threadIdx.x >> 6, lid = threadIdx.x & 63;
  if (lid == 0) { red[0][wid] = s; red[1][wid] = ss; }
  __syncthreads();
  if (threadIdx.x == 0) {
    float S = 0.f, SS = 0.f;
    for (int w = 0; w < 4; ++w) { S += red[0][w]; SS += red[1][w]; }
    part[(b*128 + blk)*2] = S; part[(b*128 + blk)*2 + 1] = SS;
  }
}

__global__ void ln_final(const float* __restrict__ part, float* __restrict__ stats) {
  int b = blockIdx.x, lid = threadIdx.x;
  float s = 0.f, ss = 0.f;
  for (int i = lid; i < 128; i += 64) { s += part[(b*128+i)*2]; ss += part[(b*128+i)*2+1]; }
  #pragma unroll
  for (int o = 32; o; o >>= 1) { s += __shfl_down(s, o); ss += __shfl_down(ss, o); }
  if (lid == 0) {
    float mean = s / (float)NPB;
    float var = ss / (float)NPB - mean*mean;
    stats[b*2] = mean; stats[b*2+1] = rsqrtf(var + 1e-5f);
  }
}

// LN apply -> tok hi/lo (b,s,c)
__global__ void ln_apply3(const float* __restrict__ x, const float* __restrict__ lnw,
                          const float* __restrict__ lnb, const float* __restrict__ stats,
                          bf16* __restrict__ th, bf16* __restrict__ tl)
{
  __shared__ float tile[32][33];
  int b = blockIdx.z;
  int s0 = blockIdx.x*32, c0 = blockIdx.y*32;
  float mean = stats[b*2], rstd = stats[b*2+1];
  int tx = threadIdx.x, ty = threadIdx.y;
  #pragma unroll
  for (int i = 0; i < 32; i += 8) {
    int c = c0 + ty + i, s = s0 + tx;
    if (s < S_) {
      long o = (long)c*S_ + s;
      tile[ty+i][tx] = (x[(long)b*NPB + o] - mean)*rstd*lnw[o] + lnb[o];
    }
  }
  __syncthreads();
  #pragma unroll
  for (int i = 0; i < 32; i += 8) {
    int s = s0 + ty + i, c = c0 + tx;
    if (s < S_) {
      float v = tile[tx][ty+i];
      bf16 h = __float2bfloat16(v);
      long o = ((long)b*S_ + s)*C_ + c;
      th[o] = h;
      tl[o] = __float2bfloat16(v - __bfloat162float(h));
    }
  }
}

// ---------------- V transpose (bf16), zero pad t in [S_, SPAD) ----------------
__global__ void vtrans(const bf16* __restrict__ qkv, bf16* __restrict__ VT) {
  __shared__ float tile[32][33];
  int z = blockIdx.z; int bb = z >> 3, h = z & 7;
  const bf16* v = qkv + (long)bb*S_*C3 + 1536 + h*DH_;
  bf16* o = VT + (long)z*DH_*SPAD;
  int t0 = blockIdx.y*32, d0 = blockIdx.x*32;
  int tx = threadIdx.x, ty = threadIdx.y;
  #pragma unroll
  for (int i = 0; i < 32; i += 8) {
    int t = t0 + ty + i, d = d0 + tx;
    float val = 0.f;
    if (t < S_ && d < DH_) val = __bfloat162float(v[(long)t*C3 + d]);
    tile[ty+i][tx] = val;
  }
  __syncthreads();
  #pragma unroll
  for (int i = 0; i < 32; i += 8) {
    int d = d0 + ty + i, t = t0 + tx;
    if (d < DH_ && t < SPAD) o[(long)d*SPAD + t] = __float2bfloat16(tile[tx][ty+i]);
  }
}

// ---------------- softmax fp32 -> P hi/lo bf16, IN PLACE over scores row ----------------
__global__ void softmax3(float* __restrict__ scores, int nrows) {
  int row = blockIdx.x*4 + (threadIdx.x >> 6);
  if (row >= nrows) return;
  int lid = threadIdx.x & 63;
  float* src = scores + (long)row*SPAD;
  float vals[12];
  float mx = -1e30f;
  #pragma unroll
  for (int i = 0; i < 12; ++i) {
    int t = i*64 + lid;
    float v = (t < S_) ? src[t] : -1e30f;
    vals[i] = v; mx = fmaxf(mx, v);
  }
  #pragma unroll
  for (int o = 32; o; o >>= 1) mx = fmaxf(mx, __shfl_xor(mx, o));
  float sum = 0.f;
  #pragma unroll
  for (int i = 0; i < 12; ++i) { float e = __expf(vals[i] - mx); vals[i] = e; sum += e; }
  #pragma unroll
  for (int o = 32; o; o >>= 1) sum += __shfl_xor(sum, o);
  float inv = 1.f / sum;
  // in-place: row's 736 floats (2944B) become 736 bf16 hi then 736 bf16 lo
  bf16* ph = (bf16*)src;
  bf16* pl = ph + SPAD;
  #pragma unroll
  for (int i = 0; i < 12; ++i) {
    int t = i*64 + lid;
    if (t < SPAD) {
      float p = (t < S_) ? vals[i]*inv : 0.f;
      bf16 h = __float2bfloat16(p);
      ph[t] = h;
      pl[t] = __float2bfloat16(p - __bfloat162float(h));
    }
  }
}

// ---------------- residual transpose-add 1 ----------------
__global__ void tadd1(const float* __restrict__ x, const float* __restrict__ oproj,
                      float* __restrict__ xattn, bf16* __restrict__ tok2,
                      float* __restrict__ tok2f)
{
  __shared__ float t_o[32][33];
  __shared__ float t_x[32][33];
  int b = blockIdx.z;
  int s0 = blockIdx.x*32, c0 = blockIdx.y*32;
  int tx = threadIdx.x, ty = threadIdx.y;
  #pragma unroll
  for (int i = 0; i < 32; i += 8) {
    int s = s0 + ty + i;
    if (s < S_) t_o[ty+i][tx] = oproj[((long)b*S_ + s)*C_ + c0 + tx];
    int s2 = s0 + tx;
    if (s2 < S_) t_x[ty+i][tx] = x[(long)b*NPB + (long)(c0+ty+i)*S_ + s2];
  }
  __syncthreads();
  #pragma unroll
  for (int i = 0; i < 32; i += 8) {
    int s = s0 + tx, c = c0 + ty + i;
    if (s < S_) xattn[(long)b*NPB + (long)c*S_ + s] = t_x[ty+i][tx] + t_o[tx][ty+i];
    int s2 = s0 + ty + i, c2 = c0 + tx;
    if (s2 < S_) {
      float v = t_x[tx][ty+i] + t_o[ty+i][tx];
      long o = ((long)b*S_ + s2)*C_ + c2;
      tok2[o] = __float2bfloat16(v);
      tok2f[o] = v;
    }
  }
}

// ---------------- residual transpose-add 2 (final output) ----------------
__global__ void tadd2(const float* __restrict__ xattn, const float* __restrict__ moe,
                      float* __restrict__ out)
{
  __shared__ float t_m[32][33];
  __shared__ float t_x[32][33];
  int b = blockIdx.z;
  int s0 = blockIdx.x*32, c0 = blockIdx.y*32;
  int tx = threadIdx.x, ty = threadIdx.y;
  #pragma unroll
  for (int i = 0; i < 32; i += 8) {
    int s = s0 + ty + i;
    if (s < S_) t_m[ty+i][tx] = moe[((long)b*S_ + s)*C_ + c0 + tx];
    int s2 = s0 + tx;
    if (s2 < S_) t_x[ty+i][tx] = xattn[(long)b*NPB + (long)(c0+ty+i)*S_ + s2];
  }
  __syncthreads();
  #pragma unroll
  for (int i = 0; i < 32; i += 8) {
    int s = s0 + tx, c = c0 + ty + i;
    if (s < S_) out[(long)b*NPB + (long)c*S_ + s] = t_x[ty+i][tx] + t_m[tx][ty+i];
  }
}

// ---------------- router: top-2 of 3 from fp32 tok2, normalized weights ----------------
__global__ void router_k(const float* __restrict__ tok2f, const float* __restrict__ rw,
                         float* __restrict__ wfull)
{
  int t = blockIdx.x*4 + (threadIdx.x >> 6);
  if (t >= MTOK) return;
  int lid = threadIdx.x & 63;
  const float* tk = tok2f + (long)t*C_;
  float a0 = 0.f, a1 = 0.f, a2 = 0.f;
  for (int i = lid; i < C_; i += 64) {
    float v = tk[i];
    a0 += v*rw[i*3+0]; a1 += v*rw[i*3+1]; a2 += v*rw[i*3+2];
  }
  #pragma unroll
  for (int o = 32; o; o >>= 1) {
    a0 += __shfl_xor(a0, o); a1 += __shfl_xor(a1, o); a2 += __shfl_xor(a2, o);
  }
  if (lid == 0) {
    float m = fmaxf(a0, fmaxf(a1, a2));
    float e0 = __expf(a0-m), e1 = __expf(a1-m), e2 = __expf(a2-m);
    int emin = 0; float pm = e0;
    if (e1 <= pm) { pm = e1; emin = 1; }
    if (e2 <= pm) { pm = e2; emin = 2; }
    float rest = e0 + e1 + e2 - pm;
    wfull[t*3+0] = (emin == 0) ? 0.f : e0/rest;
    wfull[t*3+1] = (emin == 1) ? 0.f : e1/rest;
    wfull[t*3+2] = (emin == 2) ? 0.f : e2/rest;
  }
}

// ---------------- silu(g)*u*w, in place into gate half of GU ----------------
__global__ void silu_k(bf16* __restrict__ GU, const float* __restrict__ wfull) {
  long tid8 = (long)blockIdx.x*256 + threadIdx.x;
  long idx = tid8 * 8;
  int m = (int)(idx / DK);
  int j = (int)(idx - (long)m*DK);
  int e = j >> 11;
  float w = wfull[m*3 + e];
  bf16* gp = GU + (long)m*GUN + j;
  const bf16* up = gp + DK;
  union U8 { uint4v u; bf16 h[8]; };
  U8 g8, u8, o8;
  g8.u = *(const uint4v*)gp;
  u8.u = *(const uint4v*)up;
  #pragma unroll
  for (int i = 0; i < 8; ++i) {
    float g = __bfloat162float(g8.h[i]);
    float u = __bfloat162float(u8.h[i]);
    float sg = g / (1.f + __expf(-g));
    o8.h[i] = __float2bfloat16(sg * u * w);
  }
  *(uint4v*)gp = o8.u;
}

// =============================== host ===============================
static inline void launch_gemm(hipStream_t st,
    const bf16* A, long a_rs, long a_oo, long a_oi,
    const bf16* Bt, long b_rs, long b_oo, long b_oi,
    float* Cf, bf16* Cb, long c_rs, long c_oo, long c_oi,
    int M, int N, int K, int nlim, int zdiv, int nz)
{
  dim3 g((N + 127)/128, (M + 127)/128, nz);
  gemm_bt<<<g, 256, 0, st>>>(A, a_rs, a_oo, a_oi, Bt, b_rs, b_oo, b_oi,
                             Cf, Cb, c_rs, c_oo, c_oi, M, N, K, nlim, zdiv);
}

static inline void launch_gemm3(hipStream_t st,
    const bf16* Ah, const bf16* Al, long a_rs, long a_oo, long a_oi,
    const bf16* Bh, const bf16* Bl, long b_rs, long b_oo, long b_oi,
    float* Cf, bf16* Ch, bf16* Cl, long c_rs, long c_oo, long c_oi,
    int M, int N, int K, int nlim, int zdiv, int nz)
{
  dim3 g((N + 127)/128, (M + 127)/128, nz);
  gemm3_bt<<<g, 256, 0, st>>>(Ah, Al, a_rs, a_oo, a_oi, Bh, Bl, b_rs, b_oo, b_oi,
                              Cf, Ch, Cl, c_rs, c_oo, c_oi, M, N, K, nlim, zdiv);
}

extern "C" void kernel_launch(void* const* d_in, const int* in_sizes, int n_in,
                              void* d_out, int out_size, void* d_ws, size_t ws_size,
                              hipStream_t stream)
{
  const float* x      = (const float*)d_in[0];
  const float* ln_w   = (const float*)d_in[1];
  const float* ln_b   = (const float*)d_in[2];
  const float* qkv_w  = (const float*)d_in[3];
  const float* proj_w = (const float*)d_in[4];
  const float* rout_w = (const float*)d_in[5];
  const float* gate_w = (const float*)d_in[6];
  const float* up_w   = (const float*)d_in[7];
  const float* down_w = (const float*)d_in[8];
  float* out = (float*)d_out;

  char* ws = (char*)d_ws;
  size_t off = 0;
  auto alloc = [&](size_t bytes) { size_t r = off; off += (bytes + 255) & ~(size_t)255; return r; };

  // persistent
  size_t o_stats = alloc(8*2*4);
  size_t o_part  = alloc(8*128*2*4);
  size_t o_wfull = alloc((size_t)MTOK*3*4);
  size_t o_qkvTh = alloc((size_t)C3*C_*2);
  size_t o_qkvTl = alloc((size_t)C3*C_*2);
  size_t o_prjTh = alloc((size_t)C_*C_*2);
  size_t o_prjTl = alloc((size_t)C_*C_*2);
  size_t o_guT   = alloc((size_t)GUN*C_*2);
  size_t o_downT = alloc((size_t)C_*DK*2);
  size_t o_xattn = alloc((size_t)B_*NPB*4);
  size_t o_tok2  = alloc((size_t)MTOK*C_*2);
  size_t o_tok2f = alloc((size_t)MTOK*C_*4);
  size_t big0 = off;
  // phase A (attention)
  size_t o_tokh  = alloc((size_t)MTOK*C_*2);
  size_t o_tokl  = alloc((size_t)MTOK*C_*2);
  size_t o_qkvh  = alloc((size_t)MTOK*C3*2);
  size_t o_qkvl  = alloc((size_t)MTOK*C3*2);
  size_t o_VTh   = alloc((size_t)64*DH_*SPAD*2);
  size_t o_VTl   = alloc((size_t)64*DH_*SPAD*2);
  size_t o_aoh   = alloc((size_t)MTOK*C_*2);
  size_t o_aol   = alloc((size_t)MTOK*C_*2);
  size_t o_oproj = alloc((size_t)MTOK*C_*4);
  size_t o_scores= alloc((size_t)16*S_*SPAD*4);   // per-chunk (2 batches x 8 heads)
  size_t endA = off;
  // phase B (MoE) overlaps phase A
  off = big0;
  size_t o_GU  = alloc((size_t)MTOK*GUN*2);
  size_t o_moe = alloc((size_t)MTOK*C_*4);
  size_t endB = off;
  size_t needed = endA > endB ? endA : endB;
  if (ws_size < needed) return;  // insufficient workspace: visible failure

  float* stats  = (float*)(ws + o_stats);
  float* part   = (float*)(ws + o_part);
  float* wfull  = (float*)(ws + o_wfull);
  bf16*  qkvTh  = (bf16*)(ws + o_qkvTh);
  bf16*  qkvTl  = (bf16*)(ws + o_qkvTl);
  bf16*  prjTh  = (bf16*)(ws + o_prjTh);
  bf16*  prjTl  = (bf16*)(ws + o_prjTl);
  bf16*  guT    = (bf16*)(ws + o_guT);
  bf16*  downT  = (bf16*)(ws + o_downT);
  float* xattn  = (float*)(ws + o_xattn);
  bf16*  tok2   = (bf16*)(ws + o_tok2);
  float* tok2f  = (float*)(ws + o_tok2f);
  bf16*  tokh   = (bf16*)(ws + o_tokh);
  bf16*  tokl   = (bf16*)(ws + o_tokl);
  bf16*  qkvh   = (bf16*)(ws + o_qkvh);
  bf16*  qkvl   = (bf16*)(ws + o_qkvl);
  bf16*  VTh    = (bf16*)(ws + o_VTh);
  bf16*  VTl    = (bf16*)(ws + o_VTl);
  bf16*  aoh    = (bf16*)(ws + o_aoh);
  bf16*  aol    = (bf16*)(ws + o_aol);
  float* oproj  = (float*)(ws + o_oproj);
  float* scores = (float*)(ws + o_scores);
  bf16*  GU     = (bf16*)(ws + o_GU);
  float* moe    = (float*)(ws + o_moe);

  dim3 b32(32, 8);

  // weight conversions
  wtrans3<<<dim3(72,24,1), b32, 0, stream>>>(qkv_w,  qkvTh, qkvTl, 768, 2304, 2304, 768);
  wtrans3<<<dim3(24,24,1), b32, 0, stream>>>(proj_w, prjTh, prjTl, 768, 768,  768,  768);
  wtrans<<<dim3(64,24,3), b32, 0, stream>>>(gate_w, guT, 768, 2048, 2048, 768,
                                            (long)768*2048, (long)2048*768);
  wtrans<<<dim3(64,24,3), b32, 0, stream>>>(up_w, guT + (size_t)DK*C_, 768, 2048, 2048, 768,
                                            (long)768*2048, (long)2048*768);
  wtrans<<<dim3(24,64,3), b32, 0, stream>>>(down_w, downT, 2048, 768, 768, 6144,
                                            (long)2048*768, 2048);

  // LayerNorm -> tok hi/lo (b,s,c)
  ln_partial<<<dim3(128,8), 256, 0, stream>>>(x, part);
  ln_final<<<8, 64, 0, stream>>>(part, stats);
  ln_apply3<<<dim3(23,24,8), b32, 0, stream>>>(x, ln_w, ln_b, stats, tokh, tokl);

  // qkv = tok @ qkv_w (bf16x3, hi/lo out)
  launch_gemm3(stream, tokh, tokl, C_, 0, 0, qkvTh, qkvTl, C_, 0, 0,
               nullptr, qkvh, qkvl, C3, 0, 0, MTOK, C3, C_, C3, 1, 1);

  // V^T per (b,h), zero-padded to SPAD (hi and lo)
  vtrans<<<dim3(3,23,64), b32, 0, stream>>>(qkvh, VTh);
  vtrans<<<dim3(3,23,64), b32, 0, stream>>>(qkvl, VTl);

  // attention in 4 chunks of 16 (b,h)-pairs (2 batches each)
  for (int c = 0; c < 4; ++c) {
    const long qoff = (long)(2*c)*S_*C3;
    // scores = Q K^T (fp32)
    launch_gemm3(stream,
        qkvh + qoff, qkvl + qoff, C3, (long)S_*C3, DH_,
        qkvh + qoff + 768, qkvl + qoff + 768, C3, (long)S_*C3, DH_,
        scores, nullptr, nullptr, SPAD, (long)8*S_*SPAD, (long)S_*SPAD,
        S_, S_, DH_, SPAD, 8, 16);
    // softmax, P hi/lo in place over scores
    softmax3<<<2916, 256, 0, stream>>>(scores, 16*S_);
    // attnout = P V (hi/lo out)
    bf16* Pbase = (bf16*)scores;
    launch_gemm3(stream,
        Pbase, Pbase + SPAD, 2*SPAD, (long)8*S_*2*SPAD, (long)S_*2*SPAD,
        VTh + (size_t)c*16*DH_*SPAD, VTl + (size_t)c*16*DH_*SPAD, SPAD,
        (long)8*DH_*SPAD, (long)DH_*SPAD,
        nullptr, aoh + (size_t)(2*c)*S_*C_, aol + (size_t)(2*c)*S_*C_,
        C_, (long)S_*C_, DH_,
        S_, DH_, SPAD, DH_, 8, 16);
  }

  // oproj = attnout @ proj_w (fp32 out)
  launch_gemm3(stream, aoh, aol, C_, 0, 0, prjTh, prjTl, C_, 0, 0,
               oproj, nullptr, nullptr, C_, 0, 0, MTOK, C_, C_, C_, 1, 1);

  // residual + layouts: xattn (b,c,s) fp32, tok2 bf16 + tok2f fp32 (b,s,c)
  tadd1<<<dim3(23,24,8), b32, 0, stream>>>(x, oproj, xattn, tok2, tok2f);

  // router weights (fp32 path)
  router_k<<<1458, 256, 0, stream>>>(tok2f, rout_w, wfull);

  // gate|up fused GEMM -> GU (bf16), then silu*up*w in place (gate half)
  launch_gemm(stream, tok2, C_, 0, 0, guT, C_, 0, 0,
              nullptr, GU, GUN, 0, 0, MTOK, GUN, C_, GUN, 1, 1);
  silu_k<<<17496, 256, 0, stream>>>(GU, wfull);

  // down GEMM over concatenated experts (K = 6144)
  launch_gemm(stream, GU, GUN, 0, 0, downT, DK, 0, 0,
              moe, nullptr, C_, 0, 0, MTOK, C_, DK, C_, 1, 1);

  // final residual transpose-add into output
  tadd2<<<dim3(23,24,8), b32, 0, stream>>>(xattn, moe, out);
}

// Round 3
// 932.815 us; speedup vs baseline: 1.0474x; 1.0474x over previous
//
#include <hip/hip_runtime.h>
#include <hip/hip_bf16.h>

#define C_    768
#define NH_   8
#define DH_   96
#define S_    729
#define B_    8
#define MTOK  5832
#define C3    2304
#define GUN   12288
#define DK    6144
#define SPAD  736
#define NPB   559872   // C_*S_

typedef __attribute__((ext_vector_type(8))) short short8;
typedef __attribute__((ext_vector_type(4))) float f32x4;
typedef __attribute__((ext_vector_type(4))) unsigned int uint4v;
typedef __hip_bfloat16 bf16;

__device__ __forceinline__ void gld_lds16(const bf16* g, bf16* l) {
  __builtin_amdgcn_global_load_lds((const __attribute__((address_space(1))) void*)g,
                                   (__attribute__((address_space(3))) void*)l, 16, 0, 0);
}
__device__ __forceinline__ void gld_lds16c(const char* g, char* l) {
  __builtin_amdgcn_global_load_lds((const __attribute__((address_space(1))) void*)g,
                                   (__attribute__((address_space(3))) void*)l, 16, 0, 0);
}

// ================= 256x256 8-wave 4-phase deep-pipelined GEMM =================
// C = A @ Bt^T, A[M][K] bf16 (row stride a_rs), Bt[N][K] bf16 (row stride b_rs).
// K-chunk per z: k0 = z*Ksub, Ksub % 64 == 0. Out: bf16 (Cb) or fp32 partials
// (Cf + z*c_zoff). LDS 128KiB = 2 dbuf x (A 256x64 + B 256x64) bf16, XOR-swizzled
// (byte ^= (row&7)<<4) via pre-swizzled global source (linear gld_lds dest).
__global__ void __launch_bounds__(512, 2)
gemm8(const bf16* __restrict__ A, long a_rs,
      const bf16* __restrict__ Bt, long b_rs,
      float* __restrict__ Cf, bf16* __restrict__ Cb,
      long c_rs, long c_zoff, int M, int N, int Ksub)
{
  __shared__ __attribute__((aligned(128))) char ldsc[131072];
  const int tid = threadIdx.x;
  const int wid = tid >> 6, lid = tid & 63;
  const int wm = wid >> 2, wn = wid & 3;           // 2 x 4 wave grid
  const int fr = lid & 15, g8 = (lid >> 4) * 8;
  const int brow = blockIdx.y * 256, bcol = blockIdx.x * 256;
  const long k0b = (long)blockIdx.z * Ksub * 2;    // byte offset of K-chunk
  const long a_rsb = a_rs * 2, b_rsb = b_rs * 2;
  const char* Ab = (const char*)A;
  const char* Bb = (const char*)Bt;
  const int srow = tid >> 3;                        // 0..63 staging row
  const int scol = ((tid & 7) ^ (srow & 7)) << 4;   // pre-swizzled source col byte
  const int NT = Ksub >> 6;
  const int laneA = (wm*128 + fr)*128;
  const int laneB = 32768 + (wn*64 + fr)*128;
  const int colx0 = (g8 << 1) ^ ((fr & 7) << 4);
  const int colx1 = ((32 + g8) << 1) ^ ((fr & 7) << 4);

  f32x4 acc[8][4] = {};
  short8 a4[4][2], b4[4][2];

  auto LDA = [&](int db, int mf, int j) -> short8 {
    return *(const short8*)(ldsc + db*65536 + laneA + mf*2048 + (j ? colx1 : colx0));
  };
  auto LDB = [&](int db, int nf, int j) -> short8 {
    return *(const short8*)(ldsc + db*65536 + laneB + nf*2048 + (j ? colx1 : colx0));
  };
  auto STAGE_A = [&](int kt, int h, int db) {
    const long kb = k0b + (long)kt*128;
    #pragma unroll
    for (int c2 = 0; c2 < 2; ++c2) {
      int row = brow + h*128 + c2*64 + srow;
      if (row > M-1) row = M-1;
      gld_lds16c(Ab + (long)row*a_rsb + kb + scol,
                 ldsc + db*65536 + h*16384 + c2*8192 + wid*1024);
    }
  };
  auto STAGE_B = [&](int kt, int h, int db) {
    const long kb = k0b + (long)kt*128;
    #pragma unroll
    for (int c2 = 0; c2 < 2; ++c2) {
      int row = bcol + h*128 + c2*64 + srow;
      if (row > N-1) row = N-1;
      gld_lds16c(Bb + (long)row*b_rsb + kb + scol,
                 ldsc + db*65536 + 32768 + h*16384 + c2*8192 + wid*1024);
    }
  };

  // prologue: tile0 full, plus B0(1), A0(1)
  STAGE_A(0, 0, 0); STAGE_A(0, 1, 0);
  STAGE_B(0, 0, 0); STAGE_B(0, 1, 0);
  if (NT > 1) {
    STAGE_B(1, 0, 1); STAGE_A(1, 0, 1);
    asm volatile("s_waitcnt vmcnt(4)" ::: "memory");
  } else {
    asm volatile("s_waitcnt vmcnt(0)" ::: "memory");
  }
  __builtin_amdgcn_s_barrier();

  for (int t = 0; t < NT; ++t) {
    const int db = t & 1, nb = db ^ 1;
    // ---- phase 0: Q(m0..3, n0..1) ----
    #pragma unroll
    for (int mf = 0; mf < 4; ++mf)
      #pragma unroll
      for (int j = 0; j < 2; ++j) a4[mf][j] = LDA(db, mf, j);
    #pragma unroll
    for (int nf = 0; nf < 2; ++nf)
      #pragma unroll
      for (int j = 0; j < 2; ++j) b4[nf][j] = LDB(db, nf, j);
    if (t+1 < NT) STAGE_A(t+1, 1, nb);
    __builtin_amdgcn_s_barrier();
    asm volatile("s_waitcnt lgkmcnt(0)" ::: "memory");
    __builtin_amdgcn_sched_barrier(0);
    __builtin_amdgcn_s_setprio(1);
    #pragma unroll
    for (int mf = 0; mf < 4; ++mf)
      #pragma unroll
      for (int nf = 0; nf < 2; ++nf)
        #pragma unroll
        for (int j = 0; j < 2; ++j)
          acc[mf][nf] = __builtin_amdgcn_mfma_f32_16x16x32_bf16(a4[mf][j], b4[nf][j], acc[mf][nf], 0, 0, 0);
    __builtin_amdgcn_s_setprio(0);
    __builtin_amdgcn_s_barrier();
    // ---- phase 1: Q(m0..3, n2..3) ----
    #pragma unroll
    for (int nf = 2; nf < 4; ++nf)
      #pragma unroll
      for (int j = 0; j < 2; ++j) b4[nf][j] = LDB(db, nf, j);
    if (t+1 < NT) STAGE_B(t+1, 1, nb);
    __builtin_amdgcn_s_barrier();
    asm volatile("s_waitcnt lgkmcnt(0)" ::: "memory");
    __builtin_amdgcn_sched_barrier(0);
    __builtin_amdgcn_s_setprio(1);
    #pragma unroll
    for (int mf = 0; mf < 4; ++mf)
      #pragma unroll
      for (int nf = 2; nf < 4; ++nf)
        #pragma unroll
        for (int j = 0; j < 2; ++j)
          acc[mf][nf] = __builtin_amdgcn_mfma_f32_16x16x32_bf16(a4[mf][j], b4[nf][j], acc[mf][nf], 0, 0, 0);
    __builtin_amdgcn_s_setprio(0);
    __builtin_amdgcn_s_barrier();
    // ---- phase 2: Q(m4..7, n2..3) ----
    #pragma unroll
    for (int mi = 0; mi < 4; ++mi)
      #pragma unroll
      for (int j = 0; j < 2; ++j) a4[mi][j] = LDA(db, 4+mi, j);
    if (t+2 < NT) STAGE_B(t+2, 0, db);
    __builtin_amdgcn_s_barrier();
    asm volatile("s_waitcnt lgkmcnt(0)" ::: "memory");
    __builtin_amdgcn_sched_barrier(0);
    __builtin_amdgcn_s_setprio(1);
    #pragma unroll
    for (int mi = 0; mi < 4; ++mi)
      #pragma unroll
      for (int nf = 2; nf < 4; ++nf)
        #pragma unroll
        for (int j = 0; j < 2; ++j)
          acc[4+mi][nf] = __builtin_amdgcn_mfma_f32_16x16x32_bf16(a4[mi][j], b4[nf][j], acc[4+mi][nf], 0, 0, 0);
    __builtin_amdgcn_s_setprio(0);
    __builtin_amdgcn_s_barrier();
    // ---- phase 3: Q(m4..7, n0..1) ----
    if (t+2 < NT) STAGE_A(t+2, 0, db);
    __builtin_amdgcn_s_barrier();
    __builtin_amdgcn_s_setprio(1);
    #pragma unroll
    for (int mi = 0; mi < 4; ++mi)
      #pragma unroll
      for (int nf = 0; nf < 2; ++nf)
        #pragma unroll
        for (int j = 0; j < 2; ++j)
          acc[4+mi][nf] = __builtin_amdgcn_mfma_f32_16x16x32_bf16(a4[mi][j], b4[nf][j], acc[4+mi][nf], 0, 0, 0);
    __builtin_amdgcn_s_setprio(0);
    if (t+2 < NT)      asm volatile("s_waitcnt vmcnt(4)" ::: "memory");
    else if (t+1 < NT) asm volatile("s_waitcnt vmcnt(0)" ::: "memory");
    __builtin_amdgcn_s_barrier();
  }

  const int rg = (lid >> 4) * 4;
  #pragma unroll
  for (int mf = 0; mf < 8; ++mf) {
    #pragma unroll
    for (int nf = 0; nf < 4; ++nf) {
      const int col = bcol + wn*64 + nf*16 + fr;
      if (col < N) {
        #pragma unroll
        for (int j = 0; j < 4; ++j) {
          const int row = brow + wm*128 + mf*16 + rg + j;
          if (row < M) {
            long off = (long)row*c_rs + col;
            if (Cb) Cb[off] = __float2bfloat16(acc[mf][nf][j]);
            else    Cf[(long)blockIdx.z*c_zoff + off] = acc[mf][nf][j];
          }
        }
      }
    }
  }
}

// ---------------- plain bf16 GEMM (128^2), C = A @ Bt^T ----------------
__global__ void __launch_bounds__(256)
gemm_bt(const bf16* __restrict__ A, long a_rs, long a_oo, long a_oi,
        const bf16* __restrict__ Bt, long b_rs, long b_oo, long b_oi,
        float* __restrict__ Cf, bf16* __restrict__ Cb,
        long c_rs, long c_oo, long c_oi,
        int M, int N, int K, int nlim, int zdiv)
{
  __shared__ bf16 ldsA[128*32];
  __shared__ bf16 ldsB[128*32];
  const int tid = threadIdx.x;
  const int wid = tid >> 6;
  const int lid = tid & 63;
  const int z = blockIdx.z;
  const int zo = z / zdiv, zi = z - zo*zdiv;
  A  += (long)zo*a_oo + (long)zi*a_oi;
  Bt += (long)zo*b_oo + (long)zi*b_oi;
  const long cbase = (long)zo*c_oo + (long)zi*c_oi;
  const int brow = blockIdx.y * 128;
  const int bcol = blockIdx.x * 128;

  const int ch0 = tid, ch1 = tid + 256;
  const int ar0 = ch0 >> 2, ar1 = ch1 >> 2;
  const int ak0 = (ch0 & 3) * 8, ak1 = (ch1 & 3) * 8;
  int ra0 = brow + ar0; if (ra0 > M-1) ra0 = M-1;
  int ra1 = brow + ar1; if (ra1 > M-1) ra1 = M-1;
  int rb0 = bcol + ar0; if (rb0 > N-1) rb0 = N-1;
  int rb1 = bcol + ar1; if (rb1 > N-1) rb1 = N-1;
  const bf16* pa0 = A + (long)ra0*a_rs + ak0;
  const bf16* pa1 = A + (long)ra1*a_rs + ak1;
  const bf16* pb0 = Bt + (long)rb0*b_rs + ak0;
  const bf16* pb1 = Bt + (long)rb1*b_rs + ak1;
  bf16* la0 = (bf16*)((char*)ldsA + wid*1024);
  bf16* la1 = (bf16*)((char*)ldsA + 4096 + wid*1024);
  bf16* lb0 = (bf16*)((char*)ldsB + wid*1024);
  bf16* lb1 = (bf16*)((char*)ldsB + 4096 + wid*1024);

  f32x4 acc[4][4] = {};
  const int wm = wid >> 1, wn = wid & 1;
  const int fr = lid & 15, g8 = (lid >> 4) * 8;

  for (int kt = 0; kt < K; kt += 32) {
    __syncthreads();
    gld_lds16(pa0 + kt, la0);
    gld_lds16(pa1 + kt, la1);
    gld_lds16(pb0 + kt, lb0);
    gld_lds16(pb1 + kt, lb1);
    __syncthreads();
    short8 af[4], bf[4];
    #pragma unroll
    for (int m = 0; m < 4; ++m)
      af[m] = *(const short8*)&ldsA[(wm*64 + m*16 + fr)*32 + g8];
    #pragma unroll
    for (int n = 0; n < 4; ++n)
      bf[n] = *(const short8*)&ldsB[(wn*64 + n*16 + fr)*32 + g8];
    #pragma unroll
    for (int m = 0; m < 4; ++m)
      #pragma unroll
      for (int n = 0; n < 4; ++n)
        acc[m][n] = __builtin_amdgcn_mfma_f32_16x16x32_bf16(af[m], bf[n], acc[m][n], 0, 0, 0);
  }

  const int rg = (lid >> 4) * 4;
  #pragma unroll
  for (int m = 0; m < 4; ++m) {
    #pragma unroll
    for (int n = 0; n < 4; ++n) {
      const int col = bcol + wn*64 + n*16 + fr;
      if (col < nlim) {
        #pragma unroll
        for (int j = 0; j < 4; ++j) {
          const int row = brow + wm*64 + m*16 + rg + j;
          if (row < M) {
            long off = cbase + (long)row*c_rs + col;
            if (Cb) Cb[off] = __float2bfloat16(acc[m][n][j]);
            else    Cf[off] = acc[m][n][j];
          }
        }
      }
    }
  }
}

// ---------------- bf16x3 split GEMM: A=(Ah+Al), B=(Bh+Bl), 3 products ----------------
__global__ void __launch_bounds__(256)
gemm3_bt(const bf16* __restrict__ Ah, const bf16* __restrict__ Al,
         long a_rs, long a_oo, long a_oi,
         const bf16* __restrict__ Bth, const bf16* __restrict__ Btl,
         long b_rs, long b_oo, long b_oi,
         float* __restrict__ Cf, bf16* __restrict__ Ch, bf16* __restrict__ Cl,
         long c_rs, long c_oo, long c_oi,
         int M, int N, int K, int nlim, int zdiv)
{
  __shared__ bf16 lAh[4096];
  __shared__ bf16 lAl[4096];
  __shared__ bf16 lBh[4096];
  __shared__ bf16 lBl[4096];
  const int tid = threadIdx.x;
  const int wid = tid >> 6;
  const int lid = tid & 63;
  const int z = blockIdx.z;
  const int zo = z / zdiv, zi = z - zo*zdiv;
  const long aoff = (long)zo*a_oo + (long)zi*a_oi;
  const long boff = (long)zo*b_oo + (long)zi*b_oi;
  const long cbase = (long)zo*c_oo + (long)zi*c_oi;
  const int brow = blockIdx.y * 128;
  const int bcol = blockIdx.x * 128;

  const int ch0 = tid, ch1 = tid + 256;
  int ra0 = brow + (ch0 >> 2); if (ra0 > M-1) ra0 = M-1;
  int ra1 = brow + (ch1 >> 2); if (ra1 > M-1) ra1 = M-1;
  int rb0 = bcol + (ch0 >> 2); if (rb0 > N-1) rb0 = N-1;
  int rb1 = bcol + (ch1 >> 2); if (rb1 > N-1) rb1 = N-1;
  const long ia0 = aoff + (long)ra0*a_rs + (ch0 & 3)*8;
  const long ia1 = aoff + (long)ra1*a_rs + (ch1 & 3)*8;
  const long ib0 = boff + (long)rb0*b_rs + (ch0 & 3)*8;
  const long ib1 = boff + (long)rb1*b_rs + (ch1 & 3)*8;
  bf16* dAh0 = (bf16*)((char*)lAh + wid*1024);
  bf16* dAh1 = (bf16*)((char*)lAh + 4096 + wid*1024);
  bf16* dAl0 = (bf16*)((char*)lAl + wid*1024);
  bf16* dAl1 = (bf16*)((char*)lAl + 4096 + wid*1024);
  bf16* dBh0 = (bf16*)((char*)lBh + wid*1024);
  bf16* dBh1 = (bf16*)((char*)lBh + 4096 + wid*1024);
  bf16* dBl0 = (bf16*)((char*)lBl + wid*1024);
  bf16* dBl1 = (bf16*)((char*)lBl + 4096 + wid*1024);

  f32x4 acc[4][4] = {};
  const int wm = wid >> 1, wn = wid & 1;
  const int fr = lid & 15, g8 = (lid >> 4) * 8;

  for (int kt = 0; kt < K; kt += 32) {
    __syncthreads();
    gld_lds16(Ah + ia0 + kt, dAh0);
    gld_lds16(Ah + ia1 + kt, dAh1);
    gld_lds16(Al + ia0 + kt, dAl0);
    gld_lds16(Al + ia1 + kt, dAl1);
    gld_lds16(Bth + ib0 + kt, dBh0);
    gld_lds16(Bth + ib1 + kt, dBh1);
    gld_lds16(Btl + ib0 + kt, dBl0);
    gld_lds16(Btl + ib1 + kt, dBl1);
    __syncthreads();
    short8 fah[4], fal[4], fbh[4], fbl[4];
    #pragma unroll
    for (int m = 0; m < 4; ++m) {
      int ro = (wm*64 + m*16 + fr)*32 + g8;
      fah[m] = *(const short8*)&lAh[ro];
      fal[m] = *(const short8*)&lAl[ro];
    }
    #pragma unroll
    for (int n = 0; n < 4; ++n) {
      int ro = (wn*64 + n*16 + fr)*32 + g8;
      fbh[n] = *(const short8*)&lBh[ro];
      fbl[n] = *(const short8*)&lBl[ro];
    }
    #pragma unroll
    for (int m = 0; m < 4; ++m)
      #pragma unroll
      for (int n = 0; n < 4; ++n) {
        acc[m][n] = __builtin_amdgcn_mfma_f32_16x16x32_bf16(fal[m], fbh[n], acc[m][n], 0, 0, 0);
        acc[m][n] = __builtin_amdgcn_mfma_f32_16x16x32_bf16(fah[m], fbl[n], acc[m][n], 0, 0, 0);
        acc[m][n] = __builtin_amdgcn_mfma_f32_16x16x32_bf16(fah[m], fbh[n], acc[m][n], 0, 0, 0);
      }
  }

  const int rg = (lid >> 4) * 4;
  #pragma unroll
  for (int m = 0; m < 4; ++m) {
    #pragma unroll
    for (int n = 0; n < 4; ++n) {
      const int col = bcol + wn*64 + n*16 + fr;
      if (col < nlim) {
        #pragma unroll
        for (int j = 0; j < 4; ++j) {
          const int row = brow + wm*64 + m*16 + rg + j;
          if (row < M) {
            long off = cbase + (long)row*c_rs + col;
            float v = acc[m][n][j];
            if (Cl) {
              bf16 h = __float2bfloat16(v);
              Ch[off] = h;
              Cl[off] = __float2bfloat16(v - __bfloat162float(h));
            } else if (Ch) {
              Ch[off] = __float2bfloat16(v);
            } else {
              Cf[off] = v;
            }
          }
        }
      }
    }
  }
}

// ---------------- weight transpose fp32 -> bf16 ----------------
__global__ void wtrans(const float* __restrict__ in, bf16* __restrict__ out,
                       int R, int Cc, long in_rs, long out_rs, long in_bs, long out_bs)
{
  __shared__ float tile[32][33];
  in  += (long)blockIdx.z * in_bs;
  out += (long)blockIdx.z * out_bs;
  int r0 = blockIdx.y*32, c0 = blockIdx.x*32;
  int tx = threadIdx.x, ty = threadIdx.y;
  #pragma unroll
  for (int i = 0; i < 32; i += 8) {
    int r = r0 + ty + i, c = c0 + tx;
    if (r < R && c < Cc) tile[ty+i][tx] = in[(long)r*in_rs + c];
  }
  __syncthreads();
  #pragma unroll
  for (int i = 0; i < 32; i += 8) {
    int ro = c0 + ty + i, co = r0 + tx;
    if (ro < Cc && co < R) out[(long)ro*out_rs + co] = __float2bfloat16(tile[tx][ty+i]);
  }
}

// ---------------- weight transpose fp32 -> bf16 hi/lo pair ----------------
__global__ void wtrans3(const float* __restrict__ in, bf16* __restrict__ oh, bf16* __restrict__ ol,
                        int R, int Cc, long in_rs, long out_rs)
{
  __shared__ float tile[32][33];
  int r0 = blockIdx.y*32, c0 = blockIdx.x*32;
  int tx = threadIdx.x, ty = threadIdx.y;
  #pragma unroll
  for (int i = 0; i < 32; i += 8) {
    int r = r0 + ty + i, c = c0 + tx;
    if (r < R && c < Cc) tile[ty+i][tx] = in[(long)r*in_rs + c];
  }
  __syncthreads();
  #pragma unroll
  for (int i = 0; i < 32; i += 8) {
    int ro = c0 + ty + i, co = r0 + tx;
    if (ro < Cc && co < R) {
      float v = tile[tx][ty+i];
      bf16 h = __float2bfloat16(v);
      long o = (long)ro*out_rs + co;
      oh[o] = h;
      ol[o] = __float2bfloat16(v - __bfloat162float(h));
    }
  }
}

// ---------------- LayerNorm ----------------
__global__ void ln_partial(const float* __restrict__ x, float* __restrict__ part) {
  int b = blockIdx.y, blk = blockIdx.x;
  const float* xb = x + (long)b*NPB;
  int start = blk * 4374;
  float s = 0.f, ss = 0.f;
  for (int i = start + threadIdx.x; i < start + 4374; i += 256) {
    float v = xb[i]; s += v; ss += v*v;
  }
  #pragma unroll
  for (int o = 32; o; o >>= 1) { s += __shfl_down(s, o); ss += __shfl_down(ss, o); }
  __shared__ float red[2][4];
  int wid = threadIdx.x >> 6, lid = threadIdx.x & 63;
  if (lid == 0) { red[0][wid] = s; red[1][wid] = ss; }
  __syncthreads();
  if (threadIdx.x == 0) {
    float S = 0.f, SS = 0.f;
    for (int w = 0; w < 4; ++w) { S += red[0][w]; SS += red[1][w]; }
    part[(b*128 + blk)*2] = S; part[(b*128 + blk)*2 + 1] = SS;
  }
}

__global__ void ln_final(const float* __restrict__ part, float* __restrict__ stats) {
  int b = blockIdx.x, lid = threadIdx.x;
  float s = 0.f, ss = 0.f;
  for (int i = lid; i < 128; i += 64) { s += part[(b*128+i)*2]; ss += part[(b*128+i)*2+1]; }
  #pragma unroll
  for (int o = 32; o; o >>= 1) { s += __shfl_down(s, o); ss += __shfl_down(ss, o); }
  if (lid == 0) {
    float mean = s / (float)NPB;
    float var = ss / (float)NPB - mean*mean;
    stats[b*2] = mean; stats[b*2+1] = rsqrtf(var + 1e-5f);
  }
}

__global__ void ln_apply3(const float* __restrict__ x, const float* __restrict__ lnw,
                          const float* __restrict__ lnb, const float* __restrict__ stats,
                          bf16* __restrict__ th, bf16* __restrict__ tl)
{
  __shared__ float tile[32][33];
  int b = blockIdx.z;
  int s0 = blockIdx.x*32, c0 = blockIdx.y*32;
  float mean = stats[b*2], rstd = stats[b*2+1];
  int tx = threadIdx.x, ty = threadIdx.y;
  #pragma unroll
  for (int i = 0; i < 32; i += 8) {
    int c = c0 + ty + i, s = s0 + tx;
    if (s < S_) {
      long o = (long)c*S_ + s;
      tile[ty+i][tx] = (x[(long)b*NPB + o] - mean)*rstd*lnw[o] + lnb[o];
    }
  }
  __syncthreads();
  #pragma unroll
  for (int i = 0; i < 32; i += 8) {
    int s = s0 + ty + i, c = c0 + tx;
    if (s < S_) {
      float v = tile[tx][ty+i];
      bf16 h = __float2bfloat16(v);
      long o = ((long)b*S_ + s)*C_ + c;
      th[o] = h;
      tl[o] = __float2bfloat16(v - __bfloat162float(h));
    }
  }
}

// ---------------- V transpose (bf16), zero pad t in [S_, SPAD) ----------------
__global__ void vtrans(const bf16* __restrict__ qkv, bf16* __restrict__ VT) {
  __shared__ float tile[32][33];
  int z = blockIdx.z; int bb = z >> 3, h = z & 7;
  const bf16* v = qkv + (long)bb*S_*C3 + 1536 + h*DH_;
  bf16* o = VT + (long)z*DH_*SPAD;
  int t0 = blockIdx.y*32, d0 = blockIdx.x*32;
  int tx = threadIdx.x, ty = threadIdx.y;
  #pragma unroll
  for (int i = 0; i < 32; i += 8) {
    int t = t0 + ty + i, d = d0 + tx;
    float val = 0.f;
    if (t < S_ && d < DH_) val = __bfloat162float(v[(long)t*C3 + d]);
    tile[ty+i][tx] = val;
  }
  __syncthreads();
  #pragma unroll
  for (int i = 0; i < 32; i += 8) {
    int d = d0 + ty + i, t = t0 + tx;
    if (d < DH_ && t < SPAD) o[(long)d*SPAD + t] = __float2bfloat16(tile[tx][ty+i]);
  }
}

// ---------------- softmax fp32 -> P hi/lo bf16, IN PLACE over scores row ----------------
__global__ void softmax3(float* __restrict__ scores, int nrows) {
  int row = blockIdx.x*4 + (threadIdx.x >> 6);
  if (row >= nrows) return;
  int lid = threadIdx.x & 63;
  float* src = scores + (long)row*SPAD;
  float vals[12];
  float mx = -1e30f;
  #pragma unroll
  for (int i = 0; i < 12; ++i) {
    int t = i*64 + lid;
    float v = (t < S_) ? src[t] : -1e30f;
    vals[i] = v; mx = fmaxf(mx, v);
  }
  #pragma unroll
  for (int o = 32; o; o >>= 1) mx = fmaxf(mx, __shfl_xor(mx, o));
  float sum = 0.f;
  #pragma unroll
  for (int i = 0; i < 12; ++i) { float e = __expf(vals[i] - mx); vals[i] = e; sum += e; }
  #pragma unroll
  for (int o = 32; o; o >>= 1) sum += __shfl_xor(sum, o);
  float inv = 1.f / sum;
  bf16* ph = (bf16*)src;
  bf16* pl = ph + SPAD;
  #pragma unroll
  for (int i = 0; i < 12; ++i) {
    int t = i*64 + lid;
    if (t < SPAD) {
      float p = (t < S_) ? vals[i]*inv : 0.f;
      bf16 h = __float2bfloat16(p);
      ph[t] = h;
      pl[t] = __float2bfloat16(p - __bfloat162float(h));
    }
  }
}

// ---------------- residual transpose-add 1 ----------------
__global__ void tadd1(const float* __restrict__ x, const float* __restrict__ oproj,
                      float* __restrict__ xattn, bf16* __restrict__ tok2,
                      float* __restrict__ tok2f)
{
  __shared__ float t_o[32][33];
  __shared__ float t_x[32][33];
  int b = blockIdx.z;
  int s0 = blockIdx.x*32, c0 = blockIdx.y*32;
  int tx = threadIdx.x, ty = threadIdx.y;
  #pragma unroll
  for (int i = 0; i < 32; i += 8) {
    int s = s0 + ty + i;
    if (s < S_) t_o[ty+i][tx] = oproj[((long)b*S_ + s)*C_ + c0 + tx];
    int s2 = s0 + tx;
    if (s2 < S_) t_x[ty+i][tx] = x[(long)b*NPB + (long)(c0+ty+i)*S_ + s2];
  }
  __syncthreads();
  #pragma unroll
  for (int i = 0; i < 32; i += 8) {
    int s = s0 + tx, c = c0 + ty + i;
    if (s < S_) xattn[(long)b*NPB + (long)c*S_ + s] = t_x[ty+i][tx] + t_o[tx][ty+i];
    int s2 = s0 + ty + i, c2 = c0 + tx;
    if (s2 < S_) {
      float v = t_x[tx][ty+i] + t_o[ty+i][tx];
      long o = ((long)b*S_ + s2)*C_ + c2;
      tok2[o] = __float2bfloat16(v);
      tok2f[o] = v;
    }
  }
}

// ---------------- residual transpose-add 2 (final output), sums nz moe partials ----------------
__global__ void tadd2(const float* __restrict__ xattn, const float* __restrict__ moe,
                      float* __restrict__ out, int nz)
{
  __shared__ float t_m[32][33];
  __shared__ float t_x[32][33];
  int b = blockIdx.z;
  int s0 = blockIdx.x*32, c0 = blockIdx.y*32;
  int tx = threadIdx.x, ty = threadIdx.y;
  #pragma unroll
  for (int i = 0; i < 32; i += 8) {
    int s = s0 + ty + i;
    if (s < S_) {
      long o = ((long)b*S_ + s)*C_ + c0 + tx;
      float acc = 0.f;
      for (int z = 0; z < nz; ++z) acc += moe[(long)z*MTOK*C_ + o];
      t_m[ty+i][tx] = acc;
    }
    int s2 = s0 + tx;
    if (s2 < S_) t_x[ty+i][tx] = xattn[(long)b*NPB + (long)(c0+ty+i)*S_ + s2];
  }
  __syncthreads();
  #pragma unroll
  for (int i = 0; i < 32; i += 8) {
    int s = s0 + tx, c = c0 + ty + i;
    if (s < S_) out[(long)b*NPB + (long)c*S_ + s] = t_x[ty+i][tx] + t_m[tx][ty+i];
  }
}

// ---------------- router: top-2 of 3 from fp32 tok2, normalized weights ----------------
__global__ void router_k(const float* __restrict__ tok2f, const float* __restrict__ rw,
                         float* __restrict__ wfull)
{
  int t = blockIdx.x*4 + (threadIdx.x >> 6);
  if (t >= MTOK) return;
  int lid = threadIdx.x & 63;
  const float* tk = tok2f + (long)t*C_;
  float a0 = 0.f, a1 = 0.f, a2 = 0.f;
  for (int i = lid; i < C_; i += 64) {
    float v = tk[i];
    a0 += v*rw[i*3+0]; a1 += v*rw[i*3+1]; a2 += v*rw[i*3+2];
  }
  #pragma unroll
  for (int o = 32; o; o >>= 1) {
    a0 += __shfl_xor(a0, o); a1 += __shfl_xor(a1, o); a2 += __shfl_xor(a2, o);
  }
  if (lid == 0) {
    float m = fmaxf(a0, fmaxf(a1, a2));
    float e0 = __expf(a0-m), e1 = __expf(a1-m), e2 = __expf(a2-m);
    int emin = 0; float pm = e0;
    if (e1 <= pm) { pm = e1; emin = 1; }
    if (e2 <= pm) { pm = e2; emin = 2; }
    float rest = e0 + e1 + e2 - pm;
    wfull[t*3+0] = (emin == 0) ? 0.f : e0/rest;
    wfull[t*3+1] = (emin == 1) ? 0.f : e1/rest;
    wfull[t*3+2] = (emin == 2) ? 0.f : e2/rest;
  }
}

// ---------------- silu(g)*u*w, in place into gate half of GU ----------------
__global__ void silu_k(bf16* __restrict__ GU, const float* __restrict__ wfull) {
  long tid8 = (long)blockIdx.x*256 + threadIdx.x;
  long idx = tid8 * 8;
  int m = (int)(idx / DK);
  int j = (int)(idx - (long)m*DK);
  int e = j >> 11;
  float w = wfull[m*3 + e];
  bf16* gp = GU + (long)m*GUN + j;
  const bf16* up = gp + DK;
  union U8 { uint4v u; bf16 h[8]; };
  U8 g8, u8, o8;
  g8.u = *(const uint4v*)gp;
  u8.u = *(const uint4v*)up;
  #pragma unroll
  for (int i = 0; i < 8; ++i) {
    float g = __bfloat162float(g8.h[i]);
    float u = __bfloat162float(u8.h[i]);
    float sg = g / (1.f + __expf(-g));
    o8.h[i] = __float2bfloat16(sg * u * w);
  }
  *(uint4v*)gp = o8.u;
}

// =============================== host ===============================
static inline void launch_gemm3(hipStream_t st,
    const bf16* Ah, const bf16* Al, long a_rs, long a_oo, long a_oi,
    const bf16* Bh, const bf16* Bl, long b_rs, long b_oo, long b_oi,
    float* Cf, bf16* Ch, bf16* Cl, long c_rs, long c_oo, long c_oi,
    int M, int N, int K, int nlim, int zdiv, int nz)
{
  dim3 g((N + 127)/128, (M + 127)/128, nz);
  gemm3_bt<<<g, 256, 0, st>>>(Ah, Al, a_rs, a_oo, a_oi, Bh, Bl, b_rs, b_oo, b_oi,
                              Cf, Ch, Cl, c_rs, c_oo, c_oi, M, N, K, nlim, zdiv);
}

extern "C" void kernel_launch(void* const* d_in, const int* in_sizes, int n_in,
                              void* d_out, int out_size, void* d_ws, size_t ws_size,
                              hipStream_t stream)
{
  const float* x      = (const float*)d_in[0];
  const float* ln_w   = (const float*)d_in[1];
  const float* ln_b   = (const float*)d_in[2];
  const float* qkv_w  = (const float*)d_in[3];
  const float* proj_w = (const float*)d_in[4];
  const float* rout_w = (const float*)d_in[5];
  const float* gate_w = (const float*)d_in[6];
  const float* up_w   = (const float*)d_in[7];
  const float* down_w = (const float*)d_in[8];
  float* out = (float*)d_out;

  char* ws = (char*)d_ws;
  size_t off = 0;
  auto alloc = [&](size_t bytes) { size_t r = off; off += (bytes + 255) & ~(size_t)255; return r; };

  // persistent
  size_t o_stats = alloc(8*2*4);
  size_t o_part  = alloc(8*128*2*4);
  size_t o_wfull = alloc((size_t)MTOK*3*4);
  size_t o_qkvTh = alloc((size_t)C3*C_*2);
  size_t o_qkvTl = alloc((size_t)C3*C_*2);
  size_t o_prjTh = alloc((size_t)C_*C_*2);
  size_t o_prjTl = alloc((size_t)C_*C_*2);
  size_t o_guT   = alloc((size_t)GUN*C_*2);
  size_t o_downT = alloc((size_t)C_*DK*2);
  size_t o_xattn = alloc((size_t)B_*NPB*4);
  size_t o_tok2  = alloc((size_t)MTOK*C_*2);
  size_t o_tok2f = alloc((size_t)MTOK*C_*4);
  size_t big0 = off;
  // phase A (attention)
  size_t o_tokh  = alloc((size_t)MTOK*C_*2);
  size_t o_tokl  = alloc((size_t)MTOK*C_*2);
  size_t o_qkvh  = alloc((size_t)MTOK*C3*2);
  size_t o_qkvl  = alloc((size_t)MTOK*C3*2);
  size_t o_VTh   = alloc((size_t)64*DH_*SPAD*2);
  size_t o_VTl   = alloc((size_t)64*DH_*SPAD*2);
  size_t o_aoh   = alloc((size_t)MTOK*C_*2);
  size_t o_aol   = alloc((size_t)MTOK*C_*2);
  size_t o_oproj = alloc((size_t)MTOK*C_*4);
  size_t o_scores= alloc((size_t)16*S_*SPAD*4);
  size_t endA = off;
  // phase B (MoE) overlaps phase A
  off = big0;
  size_t o_GU  = alloc((size_t)MTOK*GUN*2);
  size_t o_moe = alloc((size_t)MTOK*C_*4*4);   // up to 4 fp32 partials
  size_t endB4 = off;
  size_t endB1 = big0 + (((size_t)MTOK*GUN*2 + 255) & ~(size_t)255)
                      + (((size_t)MTOK*C_*4 + 255) & ~(size_t)255);
  // choose down-gemm K-split by available workspace
  size_t needA = endA;
  int nz;
  if (ws_size >= (endA > endB4 ? endA : endB4)) nz = 4;
  else if (ws_size >= (endA > endB1 ? endA : endB1)) nz = 1;
  else return;  // insufficient workspace: visible failure
  (void)needA;

  float* stats  = (float*)(ws + o_stats);
  float* part   = (float*)(ws + o_part);
  float* wfull  = (float*)(ws + o_wfull);
  bf16*  qkvTh  = (bf16*)(ws + o_qkvTh);
  bf16*  qkvTl  = (bf16*)(ws + o_qkvTl);
  bf16*  prjTh  = (bf16*)(ws + o_prjTh);
  bf16*  prjTl  = (bf16*)(ws + o_prjTl);
  bf16*  guT    = (bf16*)(ws + o_guT);
  bf16*  downT  = (bf16*)(ws + o_downT);
  float* xattn  = (float*)(ws + o_xattn);
  bf16*  tok2   = (bf16*)(ws + o_tok2);
  float* tok2f  = (float*)(ws + o_tok2f);
  bf16*  tokh   = (bf16*)(ws + o_tokh);
  bf16*  tokl   = (bf16*)(ws + o_tokl);
  bf16*  qkvh   = (bf16*)(ws + o_qkvh);
  bf16*  qkvl   = (bf16*)(ws + o_qkvl);
  bf16*  VTh    = (bf16*)(ws + o_VTh);
  bf16*  VTl    = (bf16*)(ws + o_VTl);
  bf16*  aoh    = (bf16*)(ws + o_aoh);
  bf16*  aol    = (bf16*)(ws + o_aol);
  float* oproj  = (float*)(ws + o_oproj);
  float* scores = (float*)(ws + o_scores);
  bf16*  GU     = (bf16*)(ws + o_GU);
  float* moe    = (float*)(ws + o_moe);

  dim3 b32(32, 8);

  // weight conversions
  wtrans3<<<dim3(72,24,1), b32, 0, stream>>>(qkv_w,  qkvTh, qkvTl, 768, 2304, 2304, 768);
  wtrans3<<<dim3(24,24,1), b32, 0, stream>>>(proj_w, prjTh, prjTl, 768, 768,  768,  768);
  wtrans<<<dim3(64,24,3), b32, 0, stream>>>(gate_w, guT, 768, 2048, 2048, 768,
                                            (long)768*2048, (long)2048*768);
  wtrans<<<dim3(64,24,3), b32, 0, stream>>>(up_w, guT + (size_t)DK*C_, 768, 2048, 2048, 768,
                                            (long)768*2048, (long)2048*768);
  wtrans<<<dim3(24,64,3), b32, 0, stream>>>(down_w, downT, 2048, 768, 768, 6144,
                                            (long)2048*768, 2048);

  // LayerNorm -> tok hi/lo (b,s,c)
  ln_partial<<<dim3(128,8), 256, 0, stream>>>(x, part);
  ln_final<<<8, 64, 0, stream>>>(part, stats);
  ln_apply3<<<dim3(23,24,8), b32, 0, stream>>>(x, ln_w, ln_b, stats, tokh, tokl);

  // qkv = tok @ qkv_w (bf16x3, hi/lo out)
  launch_gemm3(stream, tokh, tokl, C_, 0, 0, qkvTh, qkvTl, C_, 0, 0,
               nullptr, qkvh, qkvl, C3, 0, 0, MTOK, C3, C_, C3, 1, 1);

  // V^T per (b,h), zero-padded to SPAD (hi and lo)
  vtrans<<<dim3(3,23,64), b32, 0, stream>>>(qkvh, VTh);
  vtrans<<<dim3(3,23,64), b32, 0, stream>>>(qkvl, VTl);

  // attention in 4 chunks of 16 (b,h)-pairs (2 batches each)
  for (int c = 0; c < 4; ++c) {
    const long qoff = (long)(2*c)*S_*C3;
    launch_gemm3(stream,
        qkvh + qoff, qkvl + qoff, C3, (long)S_*C3, DH_,
        qkvh + qoff + 768, qkvl + qoff + 768, C3, (long)S_*C3, DH_,
        scores, nullptr, nullptr, SPAD, (long)8*S_*SPAD, (long)S_*SPAD,
        S_, S_, DH_, SPAD, 8, 16);
    softmax3<<<2916, 256, 0, stream>>>(scores, 16*S_);
    bf16* Pbase = (bf16*)scores;
    launch_gemm3(stream,
        Pbase, Pbase + SPAD, 2*SPAD, (long)8*S_*2*SPAD, (long)S_*2*SPAD,
        VTh + (size_t)c*16*DH_*SPAD, VTl + (size_t)c*16*DH_*SPAD, SPAD,
        (long)8*DH_*SPAD, (long)DH_*SPAD,
        nullptr, aoh + (size_t)(2*c)*S_*C_, aol + (size_t)(2*c)*S_*C_,
        C_, (long)S_*C_, DH_,
        S_, DH_, SPAD, DH_, 8, 16);
  }

  // oproj = attnout @ proj_w (fp32 out)
  launch_gemm3(stream, aoh, aol, C_, 0, 0, prjTh, prjTl, C_, 0, 0,
               oproj, nullptr, nullptr, C_, 0, 0, MTOK, C_, C_, C_, 1, 1);

  // residual + layouts
  tadd1<<<dim3(23,24,8), b32, 0, stream>>>(x, oproj, xattn, tok2, tok2f);

  // router weights (fp32 path)
  router_k<<<1458, 256, 0, stream>>>(tok2f, rout_w, wfull);

  // gate|up fused GEMM -> GU (bf16) via 8-phase 256^2 kernel
  gemm8<<<dim3(GUN/256, 23, 1), 512, 0, stream>>>(
      tok2, C_, guT, C_, nullptr, GU, GUN, 0, MTOK, GUN, C_);
  silu_k<<<17496, 256, 0, stream>>>(GU, wfull);

  // down GEMM (K = 6144) via 8-phase kernel, K-split into nz fp32 partials
  gemm8<<<dim3(C_/256, 23, nz), 512, 0, stream>>>(
      GU, GUN, downT, DK, moe, nullptr, C_, (long)MTOK*C_, MTOK, C_, DK/nz);

  // final residual transpose-add (sums partials) into output
  tadd2<<<dim3(23,24,8), b32, 0, stream>>>(xattn, moe, out, nz);
}